// Round 1
// baseline (403.995 us; speedup 1.0000x reference)
//
#include <hip/hip_runtime.h>

// clip_nce: Q=16384 queries, V=4096 videos, scores [Q,V] fp32, labels [Q] int.
// R5 -> R6: collapse 5 launches to 3. Evidence: rocprof top-5 dispatches are all
// >=158us harness fills => every kernel of ours is <158us => the 268MB sweep is
// <158us (>=1.7TB/s) and ~200us of the 365us total lives in the four auxiliary
// launches + graph gaps. So: init -> hipMemsetAsync; gather fused into the dense
// sweep (labels[row] is uniform per block-iter -> scalar load, matching thread
// contributes exp(s)/s from data it already loaded); final fused into reduce via
// last-block ticket (device-scope atomics + threadfence, G12/G16).

#define QN 16384
#define VN 4096
#define NB 2048
#define TB 256
#define STEP (NB * TB)                    // float4s per sweep step = 524288 (8 MB)
#define ITERS ((QN * (VN / 4)) / STEP)    // 32
#define ROWS_PER_STEP (STEP / (VN / 4))   // 512

typedef float f32x4 __attribute__((ext_vector_type(4)));

// workspace layout in floats (~8.4 MiB):
#define COLCOMP_OFF 0                     // NB*1024 compact column partials
#define ROWSUM_OFF  (NB * 1024)           // QN: sum exp per row (global atomics)
#define NOMSUM_OFF  (ROWSUM_OFF + QN)     // VN: sum exp(s) per label
#define COLSUM_OFF  (NOMSUM_OFF + VN)     // VN: column exp-sums (natural order)
#define ACC_OFF     (COLSUM_OFF + VN)     // [0]=sum log rowsum, [1]=sum s
#define TICKET_OFF  (ACC_OFF + 4)         // int ticket slot (zeroed by memset)
#define ZERO_FLOATS (QN + VN + VN + 8)    // rowsum + nomsum + colsum + acc/ticket

// Grid-stride dense sweep with NON-TEMPORAL reads, fused label-gather.
// Thread (b,t): float4 index k*STEP + b*256 + t.
//  row = k*ROWS_PER_STEP + (b>>2)  (whole block in one row per iteration)
//  columns = (b&3)*1024 + t*4 + {0..3}  (fixed for all k -> register colacc)
__global__ __launch_bounds__(256, 8) void main_pass(const float* __restrict__ scores,
                                                    const int* __restrict__ labels,
                                                    float* __restrict__ ws) {
    float* rowsum  = ws + ROWSUM_OFF;
    float* nomsum  = ws + NOMSUM_OFF;
    float* colcomp = ws + COLCOMP_OFF;
    float* acc     = ws + ACC_OFF;
    const int tid  = threadIdx.x;
    const int b    = blockIdx.x;
    const int lane = tid & 63;
    const f32x4* sp = reinterpret_cast<const f32x4*>(scores);
    const int base      = b * TB + tid;
    const int rowInStep = b >> 2;          // constant per block
    const int quarter   = b & 3;           // which 1024-col quarter this block owns

    __shared__ float rowacc[ITERS];        // per-iter row partial (LDS, 4x fewer global atomics)
    if (tid < ITERS) rowacc[tid] = 0.0f;
    __syncthreads();

    float c0 = 0.f, c1 = 0.f, c2 = 0.f, c3 = 0.f;
    float sAcc = 0.f;
    bool matched = false;

#pragma unroll 8
    for (int k = 0; k < ITERS; ++k) {
        f32x4 x = __builtin_nontemporal_load(&sp[(size_t)k * STEP + base]);
        const int row = k * ROWS_PER_STEP + rowInStep;
        const int lab = labels[row];       // uniform per block-iter -> s_load
        float e0 = __expf(x.x), e1 = __expf(x.y);
        float e2 = __expf(x.z), e3 = __expf(x.w);
        c0 += e0; c1 += e1; c2 += e2; c3 += e3;
        float rp = (e0 + e1) + (e2 + e3);
#pragma unroll
        for (int off = 32; off >= 1; off >>= 1)
            rp += __shfl_down(rp, off);
        if (lane == 0) atomicAdd(&rowacc[k], rp);   // ds_add_f32, fire-and-forget
        // fused gather: does this thread hold scores[row][lab]?
        // (uniform quarter test is a scalar branch; 3/4 of iters skip it wholesale)
        if ((lab >> 10) == quarter && ((lab >> 2) & 255) == tid) {
            const int j = lab & 3;
            const float sj = (j == 0) ? x.x : (j == 1) ? x.y : (j == 2) ? x.z : x.w;
            const float ej = (j == 0) ? e0 : (j == 1) ? e1 : (j == 2) ? e2 : e3;
            unsafeAtomicAdd(&nomsum[lab], ej);
            sAcc += sj;
            matched = true;
        }
    }

    // compact col partials: colcomp[b*256*4 + t*4 + j] <-> col (b&3)*1024 + t*4 + j
    f32x4 o; o.x = c0; o.y = c1; o.z = c2; o.w = c3;
    reinterpret_cast<f32x4*>(colcomp)[b * TB + tid] = o;

    __syncthreads();
    if (tid < ITERS)   // 4 atomics per row address total across the grid
        unsafeAtomicAdd(&rowsum[tid * ROWS_PER_STEP + rowInStep], rowacc[tid]);
    if (matched)
        unsafeAtomicAdd(&acc[1], sAcc);
}

// blocks [0,128): colsum from compact partials (8 MiB read).
//   block = q*32 + cc*8 + mg: quarter q, col-chunk cc, m-range mg
// blocks [128,192): sum log rowsum -> acc[0]
// last block through the ticket computes the final scalar (fused final_pass).
__global__ __launch_bounds__(256) void reduce_final(float* __restrict__ ws,
                                                    float* __restrict__ out) {
    const float* colcomp = ws + COLCOMP_OFF;
    const float* rowsum  = ws + ROWSUM_OFF;
    float* colsum = ws + COLSUM_OFF;
    float* nomsum = ws + NOMSUM_OFF;
    float* acc    = ws + ACC_OFF;
    int* ticket   = reinterpret_cast<int*>(ws + TICKET_OFF);
    const int tid = threadIdx.x;

    if (blockIdx.x < 128) {
        const int q  = blockIdx.x >> 5;          // column quarter 0..3
        const int cc = (blockIdx.x >> 3) & 3;    // 256-col chunk 0..3
        const int mg = blockIdx.x & 7;           // m-range 0..7
        const int c  = cc * 256 + tid;           // col within quarter [0,1024)
        float sum = 0.0f;
#pragma unroll 4
        for (int m = mg * 64; m < mg * 64 + 64; ++m)
            sum += colcomp[(size_t)(4 * m + q) * 1024 + c];
        unsafeAtomicAdd(&colsum[q * 1024 + c], sum);
    } else {
        const int idx = (blockIdx.x - 128) * 256 + tid;
        float v = __logf(rowsum[idx]);
#pragma unroll
        for (int off = 32; off >= 1; off >>= 1)
            v += __shfl_down(v, off);
        if ((tid & 63) == 0) unsafeAtomicAdd(&acc[0], v);
    }

    // last-block ticket: all 192 blocks' device-scope atomics are ordered by the
    // fence before the ticket increment; the winner finishes the reduction.
    __threadfence();
    __shared__ int amLast;
    if (tid == 0) amLast = (atomicAdd(ticket, 1) == 191);
    __syncthreads();
    if (!amLast) return;

    float local = 0.0f;
    for (int c = tid; c < VN; c += 256) {
        // read-back through the atomic path (returns old value) -> guaranteed
        // coherent view of other XCDs' atomics regardless of local L2 state.
        const float cs = atomicAdd(&colsum[c], 0.0f);
        const float ns = atomicAdd(&nomsum[c], 0.0f);
        local += __logf(cs) - __logf(ns);
    }
#pragma unroll
    for (int off = 32; off >= 1; off >>= 1)
        local += __shfl_down(local, off);
    __shared__ float red[4];
    const int wid = tid >> 6, lane = tid & 63;
    if (lane == 0) red[wid] = local;
    __syncthreads();
    if (tid == 0) {
        const float a0 = atomicAdd(&acc[0], 0.0f);
        const float a1 = atomicAdd(&acc[1], 0.0f);
        const float v2t = (red[0] + red[1]) + (red[2] + red[3]);
        // mean(log rowsum - s) + mean(log colsum - log nomsum)
        out[0] = (a0 - a1) * (1.0f / QN) + v2t * (1.0f / VN);
    }
}

extern "C" void kernel_launch(void* const* d_in, const int* in_sizes, int n_in,
                              void* d_out, int out_size, void* d_ws, size_t ws_size,
                              hipStream_t stream) {
    const float* scores = (const float*)d_in[0];
    const int*   labels = (const int*)d_in[1];
    float* ws  = (float*)d_ws;
    float* out = (float*)d_out;

    hipMemsetAsync(ws + ROWSUM_OFF, 0, ZERO_FLOATS * sizeof(float), stream);
    main_pass<<<NB, TB, 0, stream>>>(scores, labels, ws);
    reduce_final<<<192, 256, 0, stream>>>(ws, out);
}